// Round 1
// baseline (209.535 us; speedup 1.0000x reference)
//
#include <hip/hip_runtime.h>

#define S_TOKENS 16384
#define DMODEL   2048
#define NE       8
#define CAPACITY 2560
#define AUXC     0.01f

// ws layout (4-byte units):
//   [0, 16384)      int    expert idx per token
//   [16384, 32768)  float  gate per token
//   [32768, 34816)  int    exclusive prefix per 64-token span (256 spans x 8 experts)
//   [34816, 34824)  float  psum[8]  (sum of probs per expert)
//   [34824]         float  zsum     (sum of logsumexp^2)

__global__ void init_kernel(float* __restrict__ acc) {
    int t = threadIdx.x;
    if (t < 9) acc[t] = 0.0f;
}

__global__ __launch_bounds__(512, 1) void logits_kernel(
    const float* __restrict__ x, const float* __restrict__ W,
    int* __restrict__ idx_out, float* __restrict__ gate_out,
    float* __restrict__ psum, float* __restrict__ zsum) {
    // WT split: WA[j] = {W[0][j..],..W[3][j]}, WB[j] = {W[4][j],..W[7][j]}
    // Exactly 64 KB static LDS; reused as reduction scratch after main loop.
    __shared__ float4 WA[DMODEL];
    __shared__ float4 WB[DMODEL];

    const int tid  = threadIdx.x;
    const int wave = tid >> 6;
    const int lane = tid & 63;

    for (int j = tid; j < DMODEL; j += 512) {
        WA[j] = make_float4(W[j],          W[DMODEL + j],   W[2*DMODEL + j], W[3*DMODEL + j]);
        WB[j] = make_float4(W[4*DMODEL+j], W[5*DMODEL + j], W[6*DMODEL + j], W[7*DMODEL + j]);
    }
    __syncthreads();

    float pacc = 0.0f;  // lane<8: running sum of prob[lane] over this wave's tokens
    float zacc = 0.0f;  // lane==0: running sum of logsumexp^2

    // 2048 groups of 8 tokens; 512 blocks x 4 groups, contiguous per block
    for (int gi = 0; gi < 4; ++gi) {
        const int group = blockIdx.x * 4 + gi;
        const int token = group * 8 + wave;
        const float* __restrict__ xrow = x + (size_t)token * DMODEL;

        float a0=0,a1=0,a2=0,a3=0,a4=0,a5=0,a6=0,a7=0;
        #pragma unroll 8
        for (int k = 0; k < DMODEL/64; ++k) {
            float  xv = xrow[k*64 + lane];
            float4 wa = WA[k*64 + lane];
            float4 wb = WB[k*64 + lane];
            a0 += xv*wa.x; a1 += xv*wa.y; a2 += xv*wa.z; a3 += xv*wa.w;
            a4 += xv*wb.x; a5 += xv*wb.y; a6 += xv*wb.z; a7 += xv*wb.w;
        }
        // butterfly: every lane ends with all 8 full logits
        #pragma unroll
        for (int off = 32; off > 0; off >>= 1) {
            a0 += __shfl_xor(a0, off); a1 += __shfl_xor(a1, off);
            a2 += __shfl_xor(a2, off); a3 += __shfl_xor(a3, off);
            a4 += __shfl_xor(a4, off); a5 += __shfl_xor(a5, off);
            a6 += __shfl_xor(a6, off); a7 += __shfl_xor(a7, off);
        }
        // argmax (first-max like jnp.argmax), softmax stats — uniform across lanes
        float m = a0; int e = 0;
        if (a1 > m) { m = a1; e = 1; }
        if (a2 > m) { m = a2; e = 2; }
        if (a3 > m) { m = a3; e = 3; }
        if (a4 > m) { m = a4; e = 4; }
        if (a5 > m) { m = a5; e = 5; }
        if (a6 > m) { m = a6; e = 6; }
        if (a7 > m) { m = a7; e = 7; }
        float z = expf(a0-m)+expf(a1-m)+expf(a2-m)+expf(a3-m)
                + expf(a4-m)+expf(a5-m)+expf(a6-m)+expf(a7-m);
        float gate = 1.0f / z;          // exp(max-m)/z with m==max
        float lz   = m + logf(z);

        if (lane == 0) {
            idx_out[token]  = e;
            gate_out[token] = gate;
            zacc += lz * lz;
        }
        // lane e accumulates prob[e]
        float ae = a0;
        if (lane == 1) ae = a1;
        if (lane == 2) ae = a2;
        if (lane == 3) ae = a3;
        if (lane == 4) ae = a4;
        if (lane == 5) ae = a5;
        if (lane == 6) ae = a6;
        if (lane == 7) ae = a7;
        if (lane < NE) pacc += expf(ae - m) * gate;
    }

    // block-level reduction of pacc/zacc, reusing the W LDS space
    __syncthreads();
    float* red = (float*)WA;   // 64 floats used: [w*8+e]
    float* zrd = (float*)WB;   // 8 floats used: [w]
    if (lane < NE)  red[wave*8 + lane] = pacc;
    if (lane == 0)  zrd[wave] = zacc;
    __syncthreads();
    if (tid < NE) {
        float s = 0.0f;
        #pragma unroll
        for (int w = 0; w < 8; ++w) s += red[w*8 + tid];
        atomicAdd(&psum[tid], s);
    }
    if (tid == NE) {
        float s = 0.0f;
        #pragma unroll
        for (int w = 0; w < 8; ++w) s += zrd[w];
        atomicAdd(zsum, s);
    }
}

__global__ __launch_bounds__(256, 1) void scan_kernel(
    const int* __restrict__ idx, int* __restrict__ prefix,
    const float* __restrict__ psum, const float* __restrict__ zsum,
    float* __restrict__ aux_out) {
    __shared__ int arr[NE][256];
    const int t = threadIdx.x;

    // per-thread histogram of tokens [t*64, t*64+64), byte-packed (max 64 < 256)
    unsigned clo = 0, chi = 0;
    const int base = t * 64;
    #pragma unroll 8
    for (int i = 0; i < 64; ++i) {
        int e = idx[base + i];
        if (e < 4) clo += 1u << (8*e);
        else       chi += 1u << (8*(e-4));
    }
    int cnt[8];
    cnt[0] = clo & 255; cnt[1] = (clo >> 8) & 255; cnt[2] = (clo >> 16) & 255; cnt[3] = clo >> 24;
    cnt[4] = chi & 255; cnt[5] = (chi >> 8) & 255; cnt[6] = (chi >> 16) & 255; cnt[7] = chi >> 24;
    #pragma unroll
    for (int e = 0; e < NE; ++e) arr[e][t] = cnt[e];
    __syncthreads();

    // Hillis-Steele inclusive scan over 256 spans, all 8 experts per step
    for (int off = 1; off < 256; off <<= 1) {
        int v[8];
        #pragma unroll
        for (int e = 0; e < NE; ++e) v[e] = (t >= off) ? arr[e][t - off] : 0;
        __syncthreads();
        #pragma unroll
        for (int e = 0; e < NE; ++e) arr[e][t] += v[e];
        __syncthreads();
    }
    #pragma unroll
    for (int e = 0; e < NE; ++e) prefix[t*8 + e] = arr[e][t] - cnt[e];

    if (t == 0) {
        float lb = 0.0f;
        for (int e = 0; e < NE; ++e) {
            float f = (float)arr[e][255] / (float)S_TOKENS;
            float p = psum[e] / (float)S_TOKENS;
            lb += f * p;
        }
        lb *= AUXC * (float)NE;
        float zl = AUXC * (zsum[0] / (float)S_TOKENS);
        aux_out[0] = zl + lb;
    }
}

__global__ __launch_bounds__(64, 1) void output_kernel(
    const int* __restrict__ idx, const float* __restrict__ gate,
    const int* __restrict__ prefix, float* __restrict__ out) {
    const int b = blockIdx.x;    // 256 spans of 64 tokens
    const int l = threadIdx.x;   // 64 lanes
    const int token = b*64 + l;
    const int e = idx[token];

    unsigned long long mymask = 0;
    #pragma unroll
    for (int q = 0; q < NE; ++q) {
        unsigned long long msk = __ballot(e == q);
        if (e == q) mymask = msk;
    }
    unsigned long long lt = (1ull << l) - 1ull;
    int rank = prefix[b*8 + e] + __popcll(mymask & lt);

    out[token] = (float)e;
    out[S_TOKENS + token] = (rank < CAPACITY) ? gate[token] : 0.0f;
}

extern "C" void kernel_launch(void* const* d_in, const int* in_sizes, int n_in,
                              void* d_out, int out_size, void* d_ws, size_t ws_size,
                              hipStream_t stream) {
    const float* x = (const float*)d_in[0];
    const float* W = (const float*)d_in[1];
    float* out = (float*)d_out;

    int*   ws_idx    = (int*)d_ws;
    float* ws_gate   = (float*)d_ws + 16384;
    int*   ws_prefix = (int*)d_ws + 32768;
    float* ws_psum   = (float*)d_ws + 34816;   // 8 floats
    float* ws_zsum   = (float*)d_ws + 34824;   // 1 float (contiguous after psum)

    init_kernel<<<1, 64, 0, stream>>>(ws_psum);
    logits_kernel<<<512, 512, 0, stream>>>(x, W, ws_idx, ws_gate, ws_psum, ws_zsum);
    scan_kernel<<<1, 256, 0, stream>>>(ws_idx, ws_prefix, ws_psum, ws_zsum, out + 2*S_TOKENS);
    output_kernel<<<256, 64, 0, stream>>>(ws_idx, ws_gate, ws_prefix, out);
}